// Round 6
// baseline (269.302 us; speedup 1.0000x reference)
//
#include <hip/hip_runtime.h>
#include <math.h>

#define NB   64
#define T0   1024
#define CIN  128
#define HID  256
#define TGT  128
#define PRED 192
#define NROWS (NB*CIN)

typedef __attribute__((ext_vector_type(4))) float f32x4;
typedef __attribute__((ext_vector_type(8))) short s16x8;

// ---------------- workspace layout (float offsets) ----------------
static const size_t XCT_OFF    = 0;          // [64][128][1024] f32
static const size_t S1_OFF     = 8388608;    // [64][128][512]
static const size_t S2_OFF     = 12582912;   // [64][128][256]
static const size_t P0_OFF     = 14680064;   // [1024][520]
static const size_t P1_OFF     = 15212544;   // [1024][264]
static const size_t P2_OFF     = 15482880;   // [1024][136]
static const size_t PARTS2_OFF = 15622144;   // [3][16][520] row-split partials
static const size_t META_OFF   = 15647104;   // 64: freqs int[9]@0, wk f32[9]@16, sw f32[3]@32
static const size_t W2T_OFF    = 15647168;   // [128 o][128 c-swizzled] bf16 (8192 floats)
static const size_t PBS_OFF    = 15655360;   // Pb[128], S_ch[128] f32
static const size_t WSUM_OFF   = 15655616;   // [3][192] f32
static const size_t WTB_OFF    = 15656192;   // bf16 w_t (172032 floats)
static const size_t DWMIX_OFF  = 15828224;   // bf16 [8192][T] (4194304 floats)
static const size_t TP_OFF     = 20022528;   // bf16 [3][192][8192] (2359296 floats)
// end = 22381824 floats = 89.5 MB

__device__ inline unsigned short f2bf(float x) {
    union { float f; unsigned u; } v; v.f = x;
    unsigned r = (v.u + 0x7FFFu + ((v.u >> 16) & 1u)) >> 16;
    return (unsigned short)r;
}
__device__ inline float bf2f(unsigned short u) {
    union { unsigned u; float f; } v; v.u = ((unsigned)u) << 16;
    return v.f;
}

// ---------------- fused: transpose x[B,T,C]->xct[B,C,T] + pool1 + pool2 ----------------
__global__ __launch_bounds__(256) void front(const float* __restrict__ x,
        float* __restrict__ xct, float* __restrict__ s1, float* __restrict__ s2) {
    __shared__ float tile[32][33];
    int b = blockIdx.z;
    int t0 = blockIdx.x * 32, c0 = blockIdx.y * 32;
    int tx = threadIdx.x, ty = threadIdx.y;       // 32 x 8
#pragma unroll
    for (int i = 0; i < 4; i++) {
        int t = t0 + ty + i * 8, c = c0 + tx;
        tile[ty + i * 8][tx] = x[((size_t)b * T0 + t) * CIN + c];
    }
    __syncthreads();
#pragma unroll
    for (int i = 0; i < 4; i++) {
        int c = c0 + ty + i * 8, cc = ty + i * 8;
        xct[((size_t)b * CIN + c) * T0 + t0 + tx] = tile[tx][cc];
        if (tx < 16) {
            float v = 0.5f * (tile[2 * tx][cc] + tile[2 * tx + 1][cc]);
            s1[((size_t)b * CIN + c) * (T0 / 2) + t0 / 2 + tx] = v;
        }
        if (tx < 8) {
            float v = 0.25f * (tile[4 * tx][cc] + tile[4 * tx + 1][cc]
                             + tile[4 * tx + 2][cc] + tile[4 * tx + 3][cc]);
            s2[((size_t)b * CIN + c) * (T0 / 4) + t0 / 4 + tx] = v;
        }
    }
}

// ---------------- FFT: 2 real rows per complex FFT, double-stage radix-2 in LDS ----------------
#define PHYS(i) ((i) + ((i) >> 5))
template<int LOGT>
__global__ __launch_bounds__(256) void fft_amps(const float* __restrict__ xm,
                                                float* __restrict__ part, int pad) {
    constexpr int T = 1 << LOGT;
    constexpr int F = T / 2;
    __shared__ float re[T + (T >> 5)], im[T + (T >> 5)];
    __shared__ float twc[F + (F >> 5)], tws[F + (F >> 5)];
    __shared__ float acc[F + 1];
    int tid = threadIdx.x;
    for (int j = tid; j < F; j += 256) {
        float s, c;
        sincosf(-6.283185307179586f * (float)j / (float)T, &s, &c);
        twc[PHYS(j)] = c; tws[PHYS(j)] = s;
    }
    for (int i = tid; i <= F; i += 256) acc[i] = 0.f;
    __syncthreads();

    int rowbase = blockIdx.x * 8;
    for (int pr = 0; pr < 4; pr++) {
        const float* row0 = xm + (size_t)(rowbase + 2 * pr) * T;
        const float* row1 = row0 + T;
        for (int j = tid; j < T; j += 256) {
            int rv = (int)(__brev((unsigned)j) >> (32 - LOGT));
            re[PHYS(rv)] = row0[j];
            im[PHYS(rv)] = row1[j];
        }
        __syncthreads();
        for (int s = 1; s + 1 <= LOGT; s += 2) {
            int mh = 1 << (s - 1);
            if (tid < T / 4) {
                int k  = tid & (mh - 1);
                int gq = tid >> (s - 1);
                int i0 = (gq << (s + 1)) + k;
                int iA = PHYS(i0), iB = PHYS(i0 + mh);
                int iC = PHYS(i0 + 2 * mh), iD = PHYS(i0 + 3 * mh);
                int t1 = PHYS(k << (LOGT - s));
                int t2 = PHYS(k << (LOGT - s - 1));
                int t3 = PHYS((k + mh) << (LOGT - s - 1));
                float w1r = twc[t1], w1i = tws[t1];
                float w2r = twc[t2], w2i = tws[t2];
                float w3r = twc[t3], w3i = tws[t3];
                float ar = re[iA], ai = im[iA];
                float br = re[iB], bi = im[iB];
                float cr = re[iC], ci = im[iC];
                float dr = re[iD], di = im[iD];
                float tbr = w1r * br - w1i * bi, tbi = w1r * bi + w1i * br;
                float tdr = w1r * dr - w1i * di, tdi = w1r * di + w1i * dr;
                float v0r = ar + tbr, v0i = ai + tbi;
                float v1r = ar - tbr, v1i = ai - tbi;
                float v2r = cr + tdr, v2i = ci + tdi;
                float v3r = cr - tdr, v3i = ci - tdi;
                float t2r = w2r * v2r - w2i * v2i, t2i = w2r * v2i + w2i * v2r;
                float t3r = w3r * v3r - w3i * v3i, t3i = w3r * v3i + w3i * v3r;
                re[iA] = v0r + t2r; im[iA] = v0i + t2i;
                re[iC] = v0r - t2r; im[iC] = v0i - t2i;
                re[iB] = v1r + t3r; im[iB] = v1i + t3i;
                re[iD] = v1r - t3r; im[iD] = v1i - t3i;
            }
            __syncthreads();
        }
        if (LOGT & 1) {
            constexpr int s = LOGT;
            int mh = 1 << (s - 1);
            if (tid < T / 2) {
                int k  = tid & (mh - 1);
                int i1 = PHYS(tid);
                int i2 = PHYS(tid + mh);
                int tw = PHYS(k);
                float wr = twc[tw], wi = tws[tw];
                float xr = re[i2], xi = im[i2];
                float tr = wr * xr - wi * xi;
                float ti = wr * xi + wi * xr;
                float ur = re[i1], ui = im[i1];
                re[i1] = ur + tr; im[i1] = ui + ti;
                re[i2] = ur - tr; im[i2] = ui - ti;
            }
            __syncthreads();
        }
        for (int f = tid; f <= F; f += 256) {
            if (f >= 1) {
                int mf = T - f;
                float rf = re[PHYS(f)], imf = im[PHYS(f)];
                float rm = re[PHYS(mf)], imm = im[PHYS(mf)];
                float m0 = sqrtf((rf + rm) * (rf + rm) + (imf - imm) * (imf - imm));
                float m1 = sqrtf((imf + imm) * (imf + imm) + (rf - rm) * (rf - rm));
                acc[f] += 0.5f * (m0 + m1);
            }
        }
        __syncthreads();
    }
    for (int f = tid; f <= F; f += 256)
        part[(size_t)blockIdx.x * pad + f] = acc[f];
}

// ---------------- stage A: sum 64 rows per block -> parts2[s][16][520] ----------------
__global__ __launch_bounds__(256) void reduce_partA(const float* __restrict__ parts,
                                                    float* __restrict__ parts2) {
    const int PADs[3] = {520, 264, 136};
    const int Fs[3]   = {513, 257, 129};
    const size_t POFF[3] = {0, (size_t)1024 * 520, (size_t)1024 * 520 + (size_t)1024 * 264};
    int s  = blockIdx.y;
    int rs = blockIdx.z;
    int fl = threadIdx.x & 63;
    int rg = threadIdx.x >> 6;
    int f  = blockIdx.x * 64 + fl;
    bool valid = f < Fs[s];
    const float* base = parts + POFF[s];
    int pad = PADs[s];
    float sum = 0.f;
    if (valid) {
        int r0 = rs * 64 + rg * 16;
#pragma unroll
        for (int i = 0; i < 16; i++) sum += base[(size_t)(r0 + i) * pad + f];
    }
    __shared__ float red[256];
    red[threadIdx.x] = sum;
    __syncthreads();
    if (rg == 0 && valid) {
        float tot = red[fl] + red[fl + 64] + red[fl + 128] + red[fl + 192];
        parts2[(size_t)(s * 16 + rs) * 520 + f] = tot;
    }
}

__device__ inline float sum16(const float* __restrict__ p2, int m, int f) {
    const float* b = p2 + (size_t)m * 16 * 520 + f;
    float s = 0.f;
#pragma unroll
    for (int r = 0; r < 16; r++) s += b[r * 520];
    return s;
}

// ---------------- top-3: one block per scale, deterministic ----------------
__device__ inline void ins3(float v, int i, float& b0, int& c0,
                            float& b1, int& c1, float& b2, int& c2) {
    bool g0 = (v > b0) || (v == b0 && i < c0);
    bool g1 = (v > b1) || (v == b1 && i < c1);
    bool g2 = (v > b2) || (v == b2 && i < c2);
    if (g0)      { b2 = b1; c2 = c1; b1 = b0; c1 = c0; b0 = v; c0 = i; }
    else if (g1) { b2 = b1; c2 = c1; b1 = v; c1 = i; }
    else if (g2) { b2 = v; c2 = i; }
}

__global__ __launch_bounds__(256) void meta_topk(const float* __restrict__ parts2,
                          const float* __restrict__ slog,
                          int* __restrict__ freqs, float* __restrict__ wk,
                          float* __restrict__ sw) {
    __shared__ float sv[12];
    __shared__ int   si[12];
    const int Fs[3] = {513, 257, 129};
    int m = blockIdx.x;
    int tid = threadIdx.x, lane = tid & 63, wv = tid >> 6;
    int F = Fs[m];
    float b0 = -1e30f, b1 = -1e30f, b2 = -1e30f;
    int   c0 = 0x7fffffff, c1 = 0x7fffffff, c2 = 0x7fffffff;
    for (int i = tid; i < F; i += 256) {
        float v = (i == 0) ? 0.f : sum16(parts2, m, i) * (1.f / 8192.f);
        ins3(v, i, b0, c0, b1, c1, b2, c2);
    }
#pragma unroll
    for (int d = 1; d < 64; d <<= 1) {
        float o0 = __shfl_xor(b0, d), o1 = __shfl_xor(b1, d), o2 = __shfl_xor(b2, d);
        int   i0 = __shfl_xor(c0, d), i1 = __shfl_xor(c1, d), i2 = __shfl_xor(c2, d);
        ins3(o0, i0, b0, c0, b1, c1, b2, c2);
        ins3(o1, i1, b0, c0, b1, c1, b2, c2);
        ins3(o2, i2, b0, c0, b1, c1, b2, c2);
    }
    if (lane == 0) {
        sv[wv * 3 + 0] = b0; si[wv * 3 + 0] = c0;
        sv[wv * 3 + 1] = b1; si[wv * 3 + 1] = c1;
        sv[wv * 3 + 2] = b2; si[wv * 3 + 2] = c2;
    }
    __syncthreads();
    if (tid == 0) {
        float d0 = sv[0], d1 = sv[1], d2 = sv[2];
        int   e0 = si[0], e1 = si[1], e2 = si[2];
        for (int q = 3; q < 12; q++) ins3(sv[q], si[q], d0, e0, d1, e1, d2, e2);
        int fr[3] = {max(1, e0), max(1, e1), max(1, e2)};
        float av[3];
#pragma unroll
        for (int i = 0; i < 3; i++) av[i] = sum16(parts2, m, fr[i]) * (1.f / 8192.f);
        float mx = fmaxf(av[0], fmaxf(av[1], av[2]));
        float x0 = expf(av[0] - mx), x1 = expf(av[1] - mx), x2 = expf(av[2] - mx);
        float inv = 1.f / (x0 + x1 + x2);
        freqs[m * 3 + 0] = fr[0]; freqs[m * 3 + 1] = fr[1]; freqs[m * 3 + 2] = fr[2];
        wk[m * 3 + 0] = x0 * inv; wk[m * 3 + 1] = x1 * inv; wk[m * 3 + 2] = x2 * inv;
        if (m == 0) {
            float s0 = slog[0], s1 = slog[1], s2 = slog[2];
            float mx2 = fmaxf(s0, fmaxf(s1, s2));
            float e0b = expf(s0 - mx2), e1b = expf(s1 - mx2), e2b = expf(s2 - mx2);
            float inv2 = 3.f / (e0b + e1b + e2b);
            sw[0] = e0b * inv2; sw[1] = e1b * inv2; sw[2] = e2b * inv2;
        }
    }
}

// ---------------- prep: w2ot[o][c^((o&7)<<3)] = sum_h w_ch[o,h]*pw_w[h,c] (bf16) ----------------
__global__ __launch_bounds__(256) void prep_w2(const float* __restrict__ w_ch,
        const float* __restrict__ pw_w, const float* __restrict__ pw_b,
        unsigned short* __restrict__ w2ot, float* __restrict__ pbs) {
    int tid = threadIdx.x;
    if (blockIdx.x == 64) {
        if (tid < 128) {
            float pb = 0.f, s = 0.f;
            for (int h = 0; h < HID; h++) {
                float w = w_ch[tid * HID + h];
                pb += w * pw_b[h]; s += w;
            }
            pbs[tid] = pb; pbs[128 + tid] = s;
        }
        return;
    }
    int idx = blockIdx.x * 256 + tid;
    int c = idx >> 7, o = idx & 127;
    float acc = 0.f;
    for (int h = 0; h < HID; h++) acc += w_ch[o * HID + h] * pw_w[h * CIN + c];
    w2ot[o * 128 + (c ^ ((o & 7) << 3))] = f2bf(acc);
}

// ---------------- prep: w_t -> bf16 + row sums ----------------
__global__ __launch_bounds__(256) void prep_wt(const float* __restrict__ wt0,
        const float* __restrict__ wt1, const float* __restrict__ wt2,
        unsigned short* __restrict__ wtb, float* __restrict__ wsum) {
    int wid = blockIdx.x * 4 + (threadIdx.x >> 6);
    int lane = threadIdx.x & 63;
    const float* src; int T, p, m; size_t off;
    if (wid < 192)      { m = 0; p = wid;       src = wt0; T = 1024; off = 0; }
    else if (wid < 384) { m = 1; p = wid - 192; src = wt1; T = 512;  off = (size_t)192 * 1024; }
    else                { m = 2; p = wid - 384; src = wt2; T = 256;  off = (size_t)192 * 1024 + (size_t)192 * 512; }
    const float* row = src + (size_t)p * T;
    unsigned short* dst = wtb + off + (size_t)p * T;
    float s = 0.f;
    for (int j = lane; j < T; j += 64) { float v = row[j]; s += v; dst[j] = f2bf(v); }
#pragma unroll
    for (int d = 1; d < 64; d <<= 1) s += __shfl_xor(s, d);
    if (lane == 0) wsum[m * 192 + p] = s;
}

// ---------------- depthwise mix: wave=channel, stride-1 lanes, guarded rows ----------------
// Row layout per channel: [guardL | x[0..T-1] | guardR guardR2 | pad]; taps read
// unmasked consecutive addresses; validity bits (27-in-u32) mask the VALUES.
template<int T>
__global__ __launch_bounds__(256) void dwmix_k(const float* __restrict__ xm,
        const float* __restrict__ dw_w, const float* __restrict__ dw_b,
        const int* __restrict__ freqs, const float* __restrict__ wkbuf, int m,
        unsigned short* __restrict__ dwmix) {
    constexpr int CPB = 4;
    constexpr int RS  = T + 4;                 // 1 guardL + T + 2 guardR + 1 pad
    constexpr int NP  = T / 128;               // iters; 2 chains (l, l+T/2) per thread
    __shared__ float xs[CPB * RS];
    __shared__ unsigned msk[T];
    int tid = threadIdx.x;
    int b = blockIdx.y;
    int c0 = blockIdx.x * CPB;

    int pk[3]; float wkv[3];
#pragma unroll
    for (int k = 0; k < 3; k++) {
        int f = freqs[m * 3 + k];
        pk[k] = T / f;
        wkv[k] = wkbuf[m * 3 + k];
    }
    // stage rows at offset +1; zero guards
    const float* src = xm + ((size_t)b * CIN + c0) * T;
    for (int i = tid; i < CPB * (T / 4); i += 256) {
        int ch = i / (T / 4), seg = i - ch * (T / 4);
        float4 v = *(const float4*)&src[(size_t)ch * T + seg * 4];
        float* d = &xs[ch * RS + 1 + seg * 4];
        d[0] = v.x; d[1] = v.y; d[2] = v.z; d[3] = v.w;
    }
    if (tid < CPB) {
        xs[tid * RS] = 0.f;
        xs[tid * RS + 1 + T] = 0.f;
        xs[tid * RS + 2 + T] = 0.f;
    }
    // build packed 27-bit validity masks
    for (int l = tid; l < T; l += 256) {
        unsigned mm = 0;
#pragma unroll
        for (int k = 0; k < 3; k++) {
            int p = pk[k];
            int rows = (T + p - 1) / p;
            int r = l / p, cc = l - r * p;
            int q = 0;
#pragma unroll
            for (int dr = -1; dr <= 1; dr++)
#pragma unroll
                for (int dc = -1; dc <= 1; dc++, q++) {
                    int rr2 = r + dr, c2 = cc + dc;
                    int pos = l + dr * p + dc;
                    if (rr2 >= 0 && rr2 < rows && c2 >= 0 && c2 < p && pos < T)
                        mm |= 1u << (k * 9 + q);
                }
        }
        msk[l] = mm;
    }
    __syncthreads();

    int ch = tid >> 6, j = tid & 63;           // one wave = one channel
    int c = c0 + ch;
    float wk9[3][9];
#pragma unroll
    for (int k = 0; k < 3; k++)
#pragma unroll
        for (int q = 0; q < 9; q++) wk9[k][q] = wkv[k] * dw_w[c * 9 + q];
    float bias = dw_b[c];
    const float* xr = &xs[ch * RS + 1];        // logical index [-1 .. T+1]
    unsigned short* outp = dwmix + ((size_t)b * CIN + c) * T;

#pragma unroll
    for (int i = 0; i < NP; i++) {
        int l0 = i * 64 + j;
        int l1 = l0 + T / 2;
        float s0 = bias, s1 = bias;
        unsigned mm0 = msk[l0], mm1 = msk[l1];
        // dr=0 center reads shared across k
        float xm0 = xr[l0 - 1], x00 = xr[l0], xp0 = xr[l0 + 1];
        float xm1 = xr[l1 - 1], x01 = xr[l1], xp1 = xr[l1 + 1];
#pragma unroll
        for (int k = 0; k < 3; k++) {
            int p = pk[k];
            unsigned g0 = mm0 >> (k * 9), g1 = mm1 >> (k * 9);
            // row validity -> clamped bases (any tap of the row set)
            int bU0 = (g0 & 7u)    ? (l0 - p) : l0;
            int bD0 = (g0 & 448u)  ? (l0 + p) : l0;
            int bU1 = (g1 & 7u)    ? (l1 - p) : l1;
            int bD1 = (g1 & 448u)  ? (l1 + p) : l1;
            float u0a = xr[bU0 - 1], u0b = xr[bU0], u0c = xr[bU0 + 1];
            float d0a = xr[bD0 - 1], d0b = xr[bD0], d0c = xr[bD0 + 1];
            float u1a = xr[bU1 - 1], u1b = xr[bU1], u1c = xr[bU1 + 1];
            float d1a = xr[bD1 - 1], d1b = xr[bD1], d1c = xr[bD1 + 1];
            const float* w = wk9[k];
            float a0, a1;
            a0  = w[0] * ((g0 & 1u)   ? u0a : 0.f);
            a0 += w[1] * ((g0 & 2u)   ? u0b : 0.f);
            a0 += w[2] * ((g0 & 4u)   ? u0c : 0.f);
            a0 += w[3] * ((g0 & 8u)   ? xm0 : 0.f);
            a0 += w[4] * x00;                       // center always valid
            a0 += w[5] * ((g0 & 32u)  ? xp0 : 0.f);
            a0 += w[6] * ((g0 & 64u)  ? d0a : 0.f);
            a0 += w[7] * ((g0 & 128u) ? d0b : 0.f);
            a0 += w[8] * ((g0 & 256u) ? d0c : 0.f);
            a1  = w[0] * ((g1 & 1u)   ? u1a : 0.f);
            a1 += w[1] * ((g1 & 2u)   ? u1b : 0.f);
            a1 += w[2] * ((g1 & 4u)   ? u1c : 0.f);
            a1 += w[3] * ((g1 & 8u)   ? xm1 : 0.f);
            a1 += w[4] * x01;
            a1 += w[5] * ((g1 & 32u)  ? xp1 : 0.f);
            a1 += w[6] * ((g1 & 64u)  ? d1a : 0.f);
            a1 += w[7] * ((g1 & 128u) ? d1b : 0.f);
            a1 += w[8] * ((g1 & 256u) ? d1c : 0.f);
            s0 += a0; s1 += a1;
        }
        outp[l0] = f2bf(s0);
        outp[l1] = f2bf(s1);
    }
}

// ---------------- tp GEMM: C[192][8192] = A[192][T] * B[8192][T]^T (bf16 MFMA) ----------------
template<int T>
__global__ __launch_bounds__(256) void tp_gemm(const unsigned short* __restrict__ A,
        const unsigned short* __restrict__ B, unsigned short* __restrict__ C) {
    __shared__ __align__(16) unsigned short As[64 * 72];
    __shared__ __align__(16) unsigned short Bs[64 * 72];
    int tid = threadIdx.x;
    int lane = tid & 63, wave = tid >> 6;
    int wm = (wave >> 1) * 32, wn = (wave & 1) * 32;
    int p0 = blockIdx.x * 64, n0 = blockIdx.y * 64;
    f32x4 acc[2][2];
#pragma unroll
    for (int i = 0; i < 2; i++)
#pragma unroll
        for (int j = 0; j < 2; j++) acc[i][j] = (f32x4){0.f, 0.f, 0.f, 0.f};

    int r = tid >> 2, seg = tid & 3;
    const unsigned short* ga = A + (size_t)(p0 + r) * T + seg * 16;
    const unsigned short* gb = B + (size_t)(n0 + r) * T + seg * 16;
    unsigned short* la = &As[r * 72 + seg * 16];
    unsigned short* lb = &Bs[r * 72 + seg * 16];
    int fr = lane & 15, fk = (lane >> 4) * 8;

    for (int k0 = 0; k0 < T; k0 += 64) {
        __syncthreads();
        *(uint4*)la       = *(const uint4*)ga;
        *(uint4*)(la + 8) = *(const uint4*)(ga + 8);
        *(uint4*)lb       = *(const uint4*)gb;
        *(uint4*)(lb + 8) = *(const uint4*)(gb + 8);
        ga += 64; gb += 64;
        __syncthreads();
#pragma unroll
        for (int ks = 0; ks < 2; ks++) {
            int ko = ks * 32 + fk;
            s16x8 a0 = *(const s16x8*)&As[(wm + fr) * 72 + ko];
            s16x8 a1 = *(const s16x8*)&As[(wm + 16 + fr) * 72 + ko];
            s16x8 b0 = *(const s16x8*)&Bs[(wn + fr) * 72 + ko];
            s16x8 b1 = *(const s16x8*)&Bs[(wn + 16 + fr) * 72 + ko];
            acc[0][0] = __builtin_amdgcn_mfma_f32_16x16x32_bf16(a0, b0, acc[0][0], 0, 0, 0);
            acc[0][1] = __builtin_amdgcn_mfma_f32_16x16x32_bf16(a0, b1, acc[0][1], 0, 0, 0);
            acc[1][0] = __builtin_amdgcn_mfma_f32_16x16x32_bf16(a1, b0, acc[1][0], 0, 0, 0);
            acc[1][1] = __builtin_amdgcn_mfma_f32_16x16x32_bf16(a1, b1, acc[1][1], 0, 0, 0);
        }
    }
    int crow = (lane >> 4) * 4, ccol = lane & 15;
#pragma unroll
    for (int i = 0; i < 2; i++)
#pragma unroll
        for (int j = 0; j < 2; j++) {
            int col = n0 + wn + j * 16 + ccol;
#pragma unroll
            for (int reg = 0; reg < 4; reg++) {
                int row = p0 + wm + i * 16 + crow + reg;
                C[(size_t)row * 8192 + col] = f2bf(acc[i][j][reg]);
            }
        }
}

// ---------------- final: out = residual + sum_m sw_m*(W2@tp_m + biases) ----------------
__global__ __launch_bounds__(256) void final_out(const float* __restrict__ x,
        const unsigned short* __restrict__ tp, const unsigned short* __restrict__ w2ot,
        const float* __restrict__ pbs, const float* __restrict__ wsum,
        const float* __restrict__ bt0, const float* __restrict__ bt1,
        const float* __restrict__ bt2, const float* __restrict__ b_ch,
        const float* __restrict__ swb, float* __restrict__ out) {
    __shared__ unsigned short w2s[128 * 128];
    __shared__ float tpsS[32][128];
    __shared__ float wsS[32], btS[32];
    const size_t TPPL = (size_t)192 * 8192;
    int tid = threadIdx.x;
    int r0 = blockIdx.x * 32;
    float sw0 = swb[0], sw1 = swb[1], sw2 = swb[2];

#pragma unroll
    for (int i = 0; i < 8; i++)
        ((uint4*)w2s)[i * 256 + tid] = ((const uint4*)w2ot)[i * 256 + tid];
#pragma unroll
    for (int it = 0; it < 2; it++) {
        int idx = tid + it * 256;
        int rr = idx >> 4, u = idx & 15;
        int r = r0 + rr;
        int b2 = r / 192, p2 = r - b2 * 192;
        size_t base = (size_t)p2 * 8192 + (size_t)b2 * 128 + u * 8;
        uint4 q0 = *(const uint4*)&tp[base];
        uint4 q1 = *(const uint4*)&tp[TPPL + base];
        uint4 q2 = *(const uint4*)&tp[2 * TPPL + base];
        const unsigned* a0 = (const unsigned*)&q0;
        const unsigned* a1 = (const unsigned*)&q1;
        const unsigned* a2 = (const unsigned*)&q2;
        float o8[8];
#pragma unroll
        for (int w = 0; w < 4; w++) {
            o8[2 * w]     = sw0 * bf2f(a0[w] & 0xffff) + sw1 * bf2f(a1[w] & 0xffff)
                          + sw2 * bf2f(a2[w] & 0xffff);
            o8[2 * w + 1] = sw0 * bf2f(a0[w] >> 16) + sw1 * bf2f(a1[w] >> 16)
                          + sw2 * bf2f(a2[w] >> 16);
        }
        *(float4*)&tpsS[rr][u * 8]     = *(float4*)&o8[0];
        *(float4*)&tpsS[rr][u * 8 + 4] = *(float4*)&o8[4];
    }
    if (tid < 32) {
        int r = r0 + tid;
        int b2 = r / 192, p = r - b2 * 192;
        wsS[tid] = sw0 * wsum[p] + sw1 * wsum[192 + p] + sw2 * wsum[384 + p];
        btS[tid] = sw0 * bt0[p] + sw1 * bt1[p] + sw2 * bt2[p];
    }
    __syncthreads();

    int o = tid & 127, half = tid >> 7;
    int rbase = half * 16;
    float pbv  = pbs[o];
    float schv = pbs[128 + o];
    float bchv = (sw0 + sw1 + sw2) * b_ch[o];
    float acc[16];
#pragma unroll
    for (int rr = 0; rr < 16; rr++) acc[rr] = 0.f;

#pragma unroll 2
    for (int cb8 = 0; cb8 < 16; cb8++) {
        uint4 wv = *(const uint4*)&w2s[o * 128 + ((cb8 ^ (o & 7)) << 3)];
        const unsigned* aw = (const unsigned*)&wv;
        float wf[8];
#pragma unroll
        for (int w = 0; w < 4; w++) {
            wf[2 * w]     = bf2f(aw[w] & 0xffff);
            wf[2 * w + 1] = bf2f(aw[w] >> 16);
        }
        int cc = cb8 * 8;
#pragma unroll
        for (int rr = 0; rr < 16; rr++) {
            const float* tr = &tpsS[rbase + rr][cc];
            float4 t0 = *(const float4*)tr;
            float4 t1 = *(const float4*)(tr + 4);
            acc[rr] += wf[0] * t0.x + wf[1] * t0.y + wf[2] * t0.z + wf[3] * t0.w
                     + wf[4] * t1.x + wf[5] * t1.y + wf[6] * t1.z + wf[7] * t1.w;
        }
    }
#pragma unroll
    for (int rr = 0; rr < 16; rr++) {
        int r = r0 + rbase + rr;
        int b2 = r / 192, p = r - b2 * 192;
        float res = x[((size_t)b2 * T0 + (T0 - PRED) + p) * CIN + o];
        out[(size_t)r * TGT + o] = res + acc[rr] + pbv * wsS[rbase + rr]
                                 + schv * btS[rbase + rr] + bchv;
    }
}

extern "C" void kernel_launch(void* const* d_in, const int* in_sizes, int n_in,
                              void* d_out, int out_size, void* d_ws, size_t ws_size,
                              hipStream_t stream) {
    const float* x    = (const float*)d_in[0];
    const float* dw_w = (const float*)d_in[1];
    const float* dw_b = (const float*)d_in[2];
    const float* pw_w = (const float*)d_in[3];
    const float* pw_b = (const float*)d_in[4];
    const float* wt0  = (const float*)d_in[5];
    const float* bt0  = (const float*)d_in[6];
    const float* wt1  = (const float*)d_in[7];
    const float* bt1  = (const float*)d_in[8];
    const float* wt2  = (const float*)d_in[9];
    const float* bt2  = (const float*)d_in[10];
    const float* w_ch = (const float*)d_in[11];
    const float* b_ch = (const float*)d_in[12];
    const float* slog = (const float*)d_in[13];
    float* out = (float*)d_out;
    float* ws  = (float*)d_ws;

    float* xct    = ws + XCT_OFF;
    float* s1b    = ws + S1_OFF;
    float* s2b    = ws + S2_OFF;
    float* parts  = ws + P0_OFF;
    float* parts2 = ws + PARTS2_OFF;
    int*   freqs  = (int*)(ws + META_OFF);
    float* wkb    = ws + META_OFF + 16;
    float* swb    = ws + META_OFF + 32;
    unsigned short* w2tb = (unsigned short*)(ws + W2T_OFF);
    float* pbs    = ws + PBS_OFF;
    float* wsumb  = ws + WSUM_OFF;
    unsigned short* wtb  = (unsigned short*)(ws + WTB_OFF);
    unsigned short* dwm  = (unsigned short*)(ws + DWMIX_OFF);
    unsigned short* tpb  = (unsigned short*)(ws + TP_OFF);

    const size_t WT1O = (size_t)192 * 1024;
    const size_t WT2O = WT1O + (size_t)192 * 512;
    const size_t TPPL = (size_t)192 * 8192;

    front<<<dim3(32, 4, NB), dim3(32, 8, 1), 0, stream>>>(x, xct, s1b, s2b);

    fft_amps<10><<<1024, 256, 0, stream>>>(xct, parts, 520);
    fft_amps<9><<<1024, 256, 0, stream>>>(s1b, parts + (size_t)1024 * 520, 264);
    fft_amps<8><<<1024, 256, 0, stream>>>(s2b, parts + (size_t)1024 * 520 + (size_t)1024 * 264, 136);
    reduce_partA<<<dim3(9, 3, 16), 256, 0, stream>>>(parts, parts2);
    meta_topk<<<3, 256, 0, stream>>>(parts2, slog, freqs, wkb, swb);

    prep_w2<<<65, 256, 0, stream>>>(w_ch, pw_w, pw_b, w2tb, pbs);
    prep_wt<<<144, 256, 0, stream>>>(wt0, wt1, wt2, wtb, wsumb);

    // scale 0 (T=1024)
    dwmix_k<1024><<<dim3(32, NB), 256, 0, stream>>>(xct, dw_w, dw_b, freqs, wkb, 0, dwm);
    tp_gemm<1024><<<dim3(3, 128), 256, 0, stream>>>(wtb, dwm, tpb);
    // scale 1 (T=512)
    dwmix_k<512><<<dim3(32, NB), 256, 0, stream>>>(s1b, dw_w, dw_b, freqs, wkb, 1, dwm);
    tp_gemm<512><<<dim3(3, 128), 256, 0, stream>>>(wtb + WT1O, dwm, tpb + TPPL);
    // scale 2 (T=256)
    dwmix_k<256><<<dim3(32, NB), 256, 0, stream>>>(s2b, dw_w, dw_b, freqs, wkb, 2, dwm);
    tp_gemm<256><<<dim3(3, 128), 256, 0, stream>>>(wtb + WT2O, dwm, tpb + 2 * TPPL);

    final_out<<<384, 256, 0, stream>>>(x, tpb, w2tb, pbs, wsumb,
                                       bt0, bt1, bt2, b_ch, swb, out);
}

// Round 7
// 268.307 us; speedup vs baseline: 1.0037x; 1.0037x over previous
//
#include <hip/hip_runtime.h>
#include <math.h>

#define NB   64
#define T0   1024
#define CIN  128
#define HID  256
#define TGT  128
#define PRED 192
#define NROWS (NB*CIN)

typedef __attribute__((ext_vector_type(4))) float f32x4;
typedef __attribute__((ext_vector_type(8))) short s16x8;

// ---------------- workspace layout (float offsets) ----------------
static const size_t XCT_OFF    = 0;          // [64][128][1024] f32
static const size_t S1_OFF     = 8388608;    // [64][128][512]
static const size_t S2_OFF     = 12582912;   // [64][128][256]
static const size_t P0_OFF     = 14680064;   // [1024][520]
static const size_t PARTS2_OFF = 15622144;   // [3][16][520]
static const size_t META_OFF   = 15647104;   // freqs int[9]@0, wk f32[9]@16, sw f32[3]@32
static const size_t W2T_OFF    = 15647168;   // [128 o][128 c-swizzled] bf16
static const size_t PBS_OFF    = 15655360;   // Pb[128], S_ch[128]
static const size_t WSUM_OFF   = 15655616;   // [3][192]
static const size_t WTB_OFF    = 15656192;   // bf16 w_t (172032 floats)
static const size_t DWM0_OFF   = 15828224;   // bf16 [8192][1024]
static const size_t DWM1_OFF   = 20022528;   // bf16 [8192][512]
static const size_t DWM2_OFF   = 22119680;   // bf16 [8192][256]
static const size_t TP_OFF     = 23168256;   // bf16 [3][192][8192]
// end = 25527552 floats = 102 MB

__device__ inline unsigned short f2bf(float x) {
    union { float f; unsigned u; } v; v.f = x;
    unsigned r = (v.u + 0x7FFFu + ((v.u >> 16) & 1u)) >> 16;
    return (unsigned short)r;
}
__device__ inline float bf2f(unsigned short u) {
    union { unsigned u; float f; } v; v.u = ((unsigned)u) << 16;
    return v.f;
}

// ---------------- fused: transpose x[B,T,C]->xct[B,C,T] + pool1 + pool2 ----------------
__global__ __launch_bounds__(256) void front(const float* __restrict__ x,
        float* __restrict__ xct, float* __restrict__ s1, float* __restrict__ s2) {
    __shared__ float tile[32][33];
    int b = blockIdx.z;
    int t0 = blockIdx.x * 32, c0 = blockIdx.y * 32;
    int tx = threadIdx.x, ty = threadIdx.y;       // 32 x 8
#pragma unroll
    for (int i = 0; i < 4; i++) {
        int t = t0 + ty + i * 8, c = c0 + tx;
        tile[ty + i * 8][tx] = x[((size_t)b * T0 + t) * CIN + c];
    }
    __syncthreads();
#pragma unroll
    for (int i = 0; i < 4; i++) {
        int c = c0 + ty + i * 8, cc = ty + i * 8;
        xct[((size_t)b * CIN + c) * T0 + t0 + tx] = tile[tx][cc];
        if (tx < 16) {
            float v = 0.5f * (tile[2 * tx][cc] + tile[2 * tx + 1][cc]);
            s1[((size_t)b * CIN + c) * (T0 / 2) + t0 / 2 + tx] = v;
        }
        if (tx < 8) {
            float v = 0.25f * (tile[4 * tx][cc] + tile[4 * tx + 1][cc]
                             + tile[4 * tx + 2][cc] + tile[4 * tx + 3][cc]);
            s2[((size_t)b * CIN + c) * (T0 / 4) + t0 / 4 + tx] = v;
        }
    }
}

// ---------------- FFT body: 2 real rows per complex FFT, double-stage radix-2 ----------------
#define PHYS(i) ((i) + ((i) >> 5))
template<int LOGT>
__device__ __forceinline__ void fft_body(const float* __restrict__ xm,
        float* __restrict__ part, int pad,
        float* re, float* im, float* twc, float* tws, float* acc) {
    constexpr int T = 1 << LOGT;
    constexpr int F = T / 2;
    int tid = threadIdx.x;
    for (int j = tid; j < F; j += 256) {
        float s, c;
        sincosf(-6.283185307179586f * (float)j / (float)T, &s, &c);
        twc[PHYS(j)] = c; tws[PHYS(j)] = s;
    }
    for (int i = tid; i <= F; i += 256) acc[i] = 0.f;
    __syncthreads();

    int rowbase = blockIdx.x * 8;
    for (int pr = 0; pr < 4; pr++) {
        const float* row0 = xm + (size_t)(rowbase + 2 * pr) * T;
        const float* row1 = row0 + T;
        for (int j = tid; j < T; j += 256) {
            int rv = (int)(__brev((unsigned)j) >> (32 - LOGT));
            re[PHYS(rv)] = row0[j];
            im[PHYS(rv)] = row1[j];
        }
        __syncthreads();
        for (int s = 1; s + 1 <= LOGT; s += 2) {
            int mh = 1 << (s - 1);
            if (tid < T / 4) {
                int k  = tid & (mh - 1);
                int gq = tid >> (s - 1);
                int i0 = (gq << (s + 1)) + k;
                int iA = PHYS(i0), iB = PHYS(i0 + mh);
                int iC = PHYS(i0 + 2 * mh), iD = PHYS(i0 + 3 * mh);
                int t1 = PHYS(k << (LOGT - s));
                int t2 = PHYS(k << (LOGT - s - 1));
                int t3 = PHYS((k + mh) << (LOGT - s - 1));
                float w1r = twc[t1], w1i = tws[t1];
                float w2r = twc[t2], w2i = tws[t2];
                float w3r = twc[t3], w3i = tws[t3];
                float ar = re[iA], ai = im[iA];
                float br = re[iB], bi = im[iB];
                float cr = re[iC], ci = im[iC];
                float dr = re[iD], di = im[iD];
                float tbr = w1r * br - w1i * bi, tbi = w1r * bi + w1i * br;
                float tdr = w1r * dr - w1i * di, tdi = w1r * di + w1i * dr;
                float v0r = ar + tbr, v0i = ai + tbi;
                float v1r = ar - tbr, v1i = ai - tbi;
                float v2r = cr + tdr, v2i = ci + tdi;
                float v3r = cr - tdr, v3i = ci - tdi;
                float t2r = w2r * v2r - w2i * v2i, t2i = w2r * v2i + w2i * v2r;
                float t3r = w3r * v3r - w3i * v3i, t3i = w3r * v3i + w3i * v3r;
                re[iA] = v0r + t2r; im[iA] = v0i + t2i;
                re[iC] = v0r - t2r; im[iC] = v0i - t2i;
                re[iB] = v1r + t3r; im[iB] = v1i + t3i;
                re[iD] = v1r - t3r; im[iD] = v1i - t3i;
            }
            __syncthreads();
        }
        if (LOGT & 1) {
            constexpr int s = LOGT;
            int mh = 1 << (s - 1);
            if (tid < T / 2) {
                int k  = tid & (mh - 1);
                int i1 = PHYS(tid);
                int i2 = PHYS(tid + mh);
                int tw = PHYS(k);
                float wr = twc[tw], wi = tws[tw];
                float xr = re[i2], xi = im[i2];
                float tr = wr * xr - wi * xi;
                float ti = wr * xi + wi * xr;
                float ur = re[i1], ui = im[i1];
                re[i1] = ur + tr; im[i1] = ui + ti;
                re[i2] = ur - tr; im[i2] = ui - ti;
            }
            __syncthreads();
        }
        for (int f = tid; f <= F; f += 256) {
            if (f >= 1) {
                int mf = T - f;
                float rf = re[PHYS(f)], imf = im[PHYS(f)];
                float rm = re[PHYS(mf)], imm = im[PHYS(mf)];
                float m0 = sqrtf((rf + rm) * (rf + rm) + (imf - imm) * (imf - imm));
                float m1 = sqrtf((imf + imm) * (imf + imm) + (rf - rm) * (rf - rm));
                acc[f] += 0.5f * (m0 + m1);
            }
        }
        __syncthreads();
    }
    for (int f = tid; f <= F; f += 256)
        part[(size_t)blockIdx.x * pad + f] = acc[f];
}

__global__ __launch_bounds__(256) void fft_all(const float* __restrict__ xct,
        const float* __restrict__ s1, const float* __restrict__ s2,
        float* __restrict__ parts) {
    __shared__ float re[1056], im[1056], twc[528], tws[528], acc[513];
    int sc = blockIdx.y;
    if (sc == 0)
        fft_body<10>(xct, parts, 520, re, im, twc, tws, acc);
    else if (sc == 1)
        fft_body<9>(s1, parts + (size_t)1024 * 520, 264, re, im, twc, tws, acc);
    else
        fft_body<8>(s2, parts + (size_t)1024 * 520 + (size_t)1024 * 264, 136,
                    re, im, twc, tws, acc);
}

// ---------------- stage A: sum 64 rows per block -> parts2[s][16][520] ----------------
__global__ __launch_bounds__(256) void reduce_partA(const float* __restrict__ parts,
                                                    float* __restrict__ parts2) {
    const int PADs[3] = {520, 264, 136};
    const int Fs[3]   = {513, 257, 129};
    const size_t POFF[3] = {0, (size_t)1024 * 520, (size_t)1024 * 520 + (size_t)1024 * 264};
    int s  = blockIdx.y;
    int rs = blockIdx.z;
    int fl = threadIdx.x & 63;
    int rg = threadIdx.x >> 6;
    int f  = blockIdx.x * 64 + fl;
    bool valid = f < Fs[s];
    const float* base = parts + POFF[s];
    int pad = PADs[s];
    float sum = 0.f;
    if (valid) {
        int r0 = rs * 64 + rg * 16;
#pragma unroll
        for (int i = 0; i < 16; i++) sum += base[(size_t)(r0 + i) * pad + f];
    }
    __shared__ float red[256];
    red[threadIdx.x] = sum;
    __syncthreads();
    if (rg == 0 && valid) {
        float tot = red[fl] + red[fl + 64] + red[fl + 128] + red[fl + 192];
        parts2[(size_t)(s * 16 + rs) * 520 + f] = tot;
    }
}

__device__ inline float sum16(const float* __restrict__ p2, int m, int f) {
    const float* b = p2 + (size_t)m * 16 * 520 + f;
    float s = 0.f;
#pragma unroll
    for (int r = 0; r < 16; r++) s += b[r * 520];
    return s;
}

// ---------------- top-3: one block per scale, deterministic ----------------
__device__ inline void ins3(float v, int i, float& b0, int& c0,
                            float& b1, int& c1, float& b2, int& c2) {
    bool g0 = (v > b0) || (v == b0 && i < c0);
    bool g1 = (v > b1) || (v == b1 && i < c1);
    bool g2 = (v > b2) || (v == b2 && i < c2);
    if (g0)      { b2 = b1; c2 = c1; b1 = b0; c1 = c0; b0 = v; c0 = i; }
    else if (g1) { b2 = b1; c2 = c1; b1 = v; c1 = i; }
    else if (g2) { b2 = v; c2 = i; }
}

__global__ __launch_bounds__(256) void meta_topk(const float* __restrict__ parts2,
                          const float* __restrict__ slog,
                          int* __restrict__ freqs, float* __restrict__ wk,
                          float* __restrict__ sw) {
    __shared__ float sv[12];
    __shared__ int   si[12];
    const int Fs[3] = {513, 257, 129};
    int m = blockIdx.x;
    int tid = threadIdx.x, lane = tid & 63, wv = tid >> 6;
    int F = Fs[m];
    float b0 = -1e30f, b1 = -1e30f, b2 = -1e30f;
    int   c0 = 0x7fffffff, c1 = 0x7fffffff, c2 = 0x7fffffff;
    for (int i = tid; i < F; i += 256) {
        float v = (i == 0) ? 0.f : sum16(parts2, m, i) * (1.f / 8192.f);
        ins3(v, i, b0, c0, b1, c1, b2, c2);
    }
#pragma unroll
    for (int d = 1; d < 64; d <<= 1) {
        float o0 = __shfl_xor(b0, d), o1 = __shfl_xor(b1, d), o2 = __shfl_xor(b2, d);
        int   i0 = __shfl_xor(c0, d), i1 = __shfl_xor(c1, d), i2 = __shfl_xor(c2, d);
        ins3(o0, i0, b0, c0, b1, c1, b2, c2);
        ins3(o1, i1, b0, c0, b1, c1, b2, c2);
        ins3(o2, i2, b0, c0, b1, c1, b2, c2);
    }
    if (lane == 0) {
        sv[wv * 3 + 0] = b0; si[wv * 3 + 0] = c0;
        sv[wv * 3 + 1] = b1; si[wv * 3 + 1] = c1;
        sv[wv * 3 + 2] = b2; si[wv * 3 + 2] = c2;
    }
    __syncthreads();
    if (tid == 0) {
        float d0 = sv[0], d1 = sv[1], d2 = sv[2];
        int   e0 = si[0], e1 = si[1], e2 = si[2];
        for (int q = 3; q < 12; q++) ins3(sv[q], si[q], d0, e0, d1, e1, d2, e2);
        int fr[3] = {max(1, e0), max(1, e1), max(1, e2)};
        float av[3];
#pragma unroll
        for (int i = 0; i < 3; i++) av[i] = sum16(parts2, m, fr[i]) * (1.f / 8192.f);
        float mx = fmaxf(av[0], fmaxf(av[1], av[2]));
        float x0 = expf(av[0] - mx), x1 = expf(av[1] - mx), x2 = expf(av[2] - mx);
        float inv = 1.f / (x0 + x1 + x2);
        freqs[m * 3 + 0] = fr[0]; freqs[m * 3 + 1] = fr[1]; freqs[m * 3 + 2] = fr[2];
        wk[m * 3 + 0] = x0 * inv; wk[m * 3 + 1] = x1 * inv; wk[m * 3 + 2] = x2 * inv;
        if (m == 0) {
            float s0 = slog[0], s1 = slog[1], s2 = slog[2];
            float mx2 = fmaxf(s0, fmaxf(s1, s2));
            float e0b = expf(s0 - mx2), e1b = expf(s1 - mx2), e2b = expf(s2 - mx2);
            float inv2 = 3.f / (e0b + e1b + e2b);
            sw[0] = e0b * inv2; sw[1] = e1b * inv2; sw[2] = e2b * inv2;
        }
    }
}

// ---------------- prep (merged): W2 fold + biases + w_t->bf16 + row sums ----------------
__global__ __launch_bounds__(256) void prep_all(const float* __restrict__ w_ch,
        const float* __restrict__ pw_w, const float* __restrict__ pw_b,
        const float* __restrict__ wt0, const float* __restrict__ wt1,
        const float* __restrict__ wt2,
        unsigned short* __restrict__ w2ot, float* __restrict__ pbs,
        unsigned short* __restrict__ wtb, float* __restrict__ wsum) {
    int tid = threadIdx.x;
    int bx = blockIdx.x;
    if (bx < 64) {
        int idx = bx * 256 + tid;
        int c = idx >> 7, o = idx & 127;
        float acc = 0.f;
        for (int h = 0; h < HID; h++) acc += w_ch[o * HID + h] * pw_w[h * CIN + c];
        w2ot[o * 128 + (c ^ ((o & 7) << 3))] = f2bf(acc);
        return;
    }
    if (bx == 64) {
        if (tid < 128) {
            float pb = 0.f, s = 0.f;
            for (int h = 0; h < HID; h++) {
                float w = w_ch[tid * HID + h];
                pb += w * pw_b[h]; s += w;
            }
            pbs[tid] = pb; pbs[128 + tid] = s;
        }
        return;
    }
    int wid = (bx - 65) * 4 + (tid >> 6);
    int lane = tid & 63;
    const float* src; int T, p, m; size_t off;
    if (wid < 192)      { m = 0; p = wid;       src = wt0; T = 1024; off = 0; }
    else if (wid < 384) { m = 1; p = wid - 192; src = wt1; T = 512;  off = (size_t)192 * 1024; }
    else                { m = 2; p = wid - 384; src = wt2; T = 256;  off = (size_t)192 * 1024 + (size_t)192 * 512; }
    const float* row = src + (size_t)p * T;
    unsigned short* dst = wtb + off + (size_t)p * T;
    float s = 0.f;
    for (int j = lane; j < T; j += 64) { float v = row[j]; s += v; dst[j] = f2bf(v); }
#pragma unroll
    for (int d = 1; d < 64; d <<= 1) s += __shfl_xor(s, d);
    if (lane == 0) wsum[m * 192 + p] = s;
}

// ---------------- depthwise mix body: R5 dataflow, stride-1 lanes ----------------
template<int T>
__device__ __forceinline__ void dwmix_body(const float* __restrict__ xm,
        const float* __restrict__ dw_w, const float* __restrict__ dw_b,
        const int* __restrict__ freqs, const float* __restrict__ wkbuf, int m,
        unsigned short* __restrict__ dwmix, float* xs, unsigned* msk) {
    constexpr int CPB = 4;
    constexpr int RS  = T + 4;
    constexpr int NP  = T / 128;               // 2 chains (l, l+T/2) per thread per iter
    int tid = threadIdx.x;
    int b = blockIdx.y;
    int c0 = blockIdx.x * CPB;

    int pk[3]; float wkv[3];
#pragma unroll
    for (int k = 0; k < 3; k++) {
        int f = freqs[m * 3 + k];
        pk[k] = T / f;
        wkv[k] = wkbuf[m * 3 + k];
    }
    // stage CPB rows (float4) + zero slot at logical index T
    const float* src = xm + ((size_t)b * CIN + c0) * T;
    for (int i = tid; i < CPB * (T / 4); i += 256) {
        int ch = i / (T / 4), seg = i - ch * (T / 4);
        *(float4*)&xs[ch * RS + seg * 4] = *(const float4*)&src[(size_t)ch * T + seg * 4];
    }
    if (tid < CPB) {
        xs[tid * RS + T]     = 0.f;
        xs[tid * RS + T + 1] = 0.f;
        xs[tid * RS + T + 2] = 0.f;
        xs[tid * RS + T + 3] = 0.f;
    }
    // packed 27-bit validity masks
    for (int l = tid; l < T; l += 256) {
        unsigned mm = 0;
#pragma unroll
        for (int k = 0; k < 3; k++) {
            int p = pk[k];
            int rows = (T + p - 1) / p;
            int r = l / p, cc = l - r * p;
            int q = 0;
#pragma unroll
            for (int dr = -1; dr <= 1; dr++)
#pragma unroll
                for (int dc = -1; dc <= 1; dc++, q++) {
                    int rr2 = r + dr, c2 = cc + dc;
                    int pos = l + dr * p + dc;
                    if (rr2 >= 0 && rr2 < rows && c2 >= 0 && c2 < p && pos < T)
                        mm |= 1u << (k * 9 + q);
                }
        }
        msk[l] = mm;
    }
    __syncthreads();

    int ch = tid >> 6, j = tid & 63;           // one wave = one channel
    int c = c0 + ch;
    float wk9[27];
#pragma unroll
    for (int k = 0; k < 3; k++)
#pragma unroll
        for (int q = 0; q < 9; q++) wk9[k * 9 + q] = wkv[k] * dw_w[c * 9 + q];
    float bias = dw_b[c];
    const int cb = ch * RS;
    unsigned short* outp = dwmix + ((size_t)b * CIN + c) * T;

#pragma unroll
    for (int i = 0; i < NP; i++) {
        int l0 = i * 64 + j;                   // stride-1 across lanes
        int l1 = l0 + T / 2;
        unsigned mm0 = msk[l0], mm1 = msk[l1];
        float s0 = bias, s1 = bias;
#pragma unroll
        for (int k = 0; k < 3; k++) {
            int p = pk[k];
            int q = k * 9;
#pragma unroll
            for (int dr = -1; dr <= 1; dr++) {
                int r0 = l0 + dr * p, r1 = l1 + dr * p;
#pragma unroll
                for (int dc = -1; dc <= 1; dc++, q++) {
                    int i0 = ((mm0 >> q) & 1) ? (r0 + dc) : T;
                    int i1 = ((mm1 >> q) & 1) ? (r1 + dc) : T;
                    s0 += wk9[q] * xs[cb + i0];
                    s1 += wk9[q] * xs[cb + i1];
                }
            }
        }
        outp[l0] = f2bf(s0);
        outp[l1] = f2bf(s1);
    }
}

__global__ __launch_bounds__(256) void dwmix_all(const float* __restrict__ xct,
        const float* __restrict__ s1, const float* __restrict__ s2,
        const float* __restrict__ dw_w, const float* __restrict__ dw_b,
        const int* __restrict__ freqs, const float* __restrict__ wkbuf,
        unsigned short* __restrict__ dwm0, unsigned short* __restrict__ dwm1,
        unsigned short* __restrict__ dwm2) {
    __shared__ float xs[4 * 1028];
    __shared__ unsigned msk[1024];
    int sc = blockIdx.z;
    if (sc == 0)      dwmix_body<1024>(xct, dw_w, dw_b, freqs, wkbuf, 0, dwm0, xs, msk);
    else if (sc == 1) dwmix_body<512>(s1,  dw_w, dw_b, freqs, wkbuf, 1, dwm1, xs, msk);
    else              dwmix_body<256>(s2,  dw_w, dw_b, freqs, wkbuf, 2, dwm2, xs, msk);
}

// ---------------- tp GEMM body: C[192][8192] = A[192][T] * B[8192][T]^T ----------------
template<int T>
__device__ __forceinline__ void gemm_body(const unsigned short* __restrict__ A,
        const unsigned short* __restrict__ B, unsigned short* __restrict__ C,
        unsigned short* As, unsigned short* Bs) {
    int tid = threadIdx.x;
    int lane = tid & 63, wave = tid >> 6;
    int wm = (wave >> 1) * 32, wn = (wave & 1) * 32;
    int p0 = blockIdx.x * 64, n0 = blockIdx.y * 64;
    f32x4 acc[2][2];
#pragma unroll
    for (int i = 0; i < 2; i++)
#pragma unroll
        for (int j = 0; j < 2; j++) acc[i][j] = (f32x4){0.f, 0.f, 0.f, 0.f};

    int r = tid >> 2, seg = tid & 3;
    const unsigned short* ga = A + (size_t)(p0 + r) * T + seg * 16;
    const unsigned short* gb = B + (size_t)(n0 + r) * T + seg * 16;
    unsigned short* la = &As[r * 72 + seg * 16];
    unsigned short* lb = &Bs[r * 72 + seg * 16];
    int fr = lane & 15, fk = (lane >> 4) * 8;

    for (int k0 = 0; k0 < T; k0 += 64) {
        __syncthreads();
        *(uint4*)la       = *(const uint4*)ga;
        *(uint4*)(la + 8) = *(const uint4*)(ga + 8);
        *(uint4*)lb       = *(const uint4*)gb;
        *(uint4*)(lb + 8) = *(const uint4*)(gb + 8);
        ga += 64; gb += 64;
        __syncthreads();
#pragma unroll
        for (int ks = 0; ks < 2; ks++) {
            int ko = ks * 32 + fk;
            s16x8 a0 = *(const s16x8*)&As[(wm + fr) * 72 + ko];
            s16x8 a1 = *(const s16x8*)&As[(wm + 16 + fr) * 72 + ko];
            s16x8 b0 = *(const s16x8*)&Bs[(wn + fr) * 72 + ko];
            s16x8 b1 = *(const s16x8*)&Bs[(wn + 16 + fr) * 72 + ko];
            acc[0][0] = __builtin_amdgcn_mfma_f32_16x16x32_bf16(a0, b0, acc[0][0], 0, 0, 0);
            acc[0][1] = __builtin_amdgcn_mfma_f32_16x16x32_bf16(a0, b1, acc[0][1], 0, 0, 0);
            acc[1][0] = __builtin_amdgcn_mfma_f32_16x16x32_bf16(a1, b0, acc[1][0], 0, 0, 0);
            acc[1][1] = __builtin_amdgcn_mfma_f32_16x16x32_bf16(a1, b1, acc[1][1], 0, 0, 0);
        }
    }
    int crow = (lane >> 4) * 4, ccol = lane & 15;
#pragma unroll
    for (int i = 0; i < 2; i++)
#pragma unroll
        for (int j = 0; j < 2; j++) {
            int col = n0 + wn + j * 16 + ccol;
#pragma unroll
            for (int reg = 0; reg < 4; reg++) {
                int row = p0 + wm + i * 16 + crow + reg;
                C[(size_t)row * 8192 + col] = f2bf(acc[i][j][reg]);
            }
        }
}

__global__ __launch_bounds__(256) void tp_gemm_all(const unsigned short* __restrict__ wtb,
        const unsigned short* __restrict__ dwm0, const unsigned short* __restrict__ dwm1,
        const unsigned short* __restrict__ dwm2, unsigned short* __restrict__ tpb) {
    __shared__ __align__(16) unsigned short As[64 * 72];
    __shared__ __align__(16) unsigned short Bs[64 * 72];
    const size_t WT1O = (size_t)192 * 1024;
    const size_t WT2O = WT1O + (size_t)192 * 512;
    const size_t TPPL = (size_t)192 * 8192;
    int sc = blockIdx.z;
    if (sc == 0)      gemm_body<1024>(wtb,        dwm0, tpb,            As, Bs);
    else if (sc == 1) gemm_body<512>(wtb + WT1O,  dwm1, tpb + TPPL,     As, Bs);
    else              gemm_body<256>(wtb + WT2O,  dwm2, tpb + 2 * TPPL, As, Bs);
}

// ---------------- final: out = residual + sum_m sw_m*(W2@tp_m + biases) ----------------
__global__ __launch_bounds__(256) void final_out(const float* __restrict__ x,
        const unsigned short* __restrict__ tp, const unsigned short* __restrict__ w2ot,
        const float* __restrict__ pbs, const float* __restrict__ wsum,
        const float* __restrict__ bt0, const float* __restrict__ bt1,
        const float* __restrict__ bt2, const float* __restrict__ b_ch,
        const float* __restrict__ swb, float* __restrict__ out) {
    __shared__ unsigned short w2s[128 * 128];
    __shared__ float tpsS[32][128];
    __shared__ float wsS[32], btS[32];
    const size_t TPPL = (size_t)192 * 8192;
    int tid = threadIdx.x;
    int r0 = blockIdx.x * 32;
    float sw0 = swb[0], sw1 = swb[1], sw2 = swb[2];

#pragma unroll
    for (int i = 0; i < 8; i++)
        ((uint4*)w2s)[i * 256 + tid] = ((const uint4*)w2ot)[i * 256 + tid];
#pragma unroll
    for (int it = 0; it < 2; it++) {
        int idx = tid + it * 256;
        int rr = idx >> 4, u = idx & 15;
        int r = r0 + rr;
        int b2 = r / 192, p2 = r - b2 * 192;
        size_t base = (size_t)p2 * 8192 + (size_t)b2 * 128 + u * 8;
        uint4 q0 = *(const uint4*)&tp[base];
        uint4 q1 = *(const uint4*)&tp[TPPL + base];
        uint4 q2 = *(const uint4*)&tp[2 * TPPL + base];
        const unsigned* a0 = (const unsigned*)&q0;
        const unsigned* a1 = (const unsigned*)&q1;
        const unsigned* a2 = (const unsigned*)&q2;
        float o8[8];
#pragma unroll
        for (int w = 0; w < 4; w++) {
            o8[2 * w]     = sw0 * bf2f(a0[w] & 0xffff) + sw1 * bf2f(a1[w] & 0xffff)
                          + sw2 * bf2f(a2[w] & 0xffff);
            o8[2 * w + 1] = sw0 * bf2f(a0[w] >> 16) + sw1 * bf2f(a1[w] >> 16)
                          + sw2 * bf2f(a2[w] >> 16);
        }
        *(float4*)&tpsS[rr][u * 8]     = *(float4*)&o8[0];
        *(float4*)&tpsS[rr][u * 8 + 4] = *(float4*)&o8[4];
    }
    if (tid < 32) {
        int r = r0 + tid;
        int b2 = r / 192, p = r - b2 * 192;
        wsS[tid] = sw0 * wsum[p] + sw1 * wsum[192 + p] + sw2 * wsum[384 + p];
        btS[tid] = sw0 * bt0[p] + sw1 * bt1[p] + sw2 * bt2[p];
    }
    __syncthreads();

    int o = tid & 127, half = tid >> 7;
    int rbase = half * 16;
    float pbv  = pbs[o];
    float schv = pbs[128 + o];
    float bchv = (sw0 + sw1 + sw2) * b_ch[o];
    float acc[16];
#pragma unroll
    for (int rr = 0; rr < 16; rr++) acc[rr] = 0.f;

#pragma unroll 2
    for (int cb8 = 0; cb8 < 16; cb8++) {
        uint4 wv = *(const uint4*)&w2s[o * 128 + ((cb8 ^ (o & 7)) << 3)];
        const unsigned* aw = (const unsigned*)&wv;
        float wf[8];
#pragma unroll
        for (int w = 0; w < 4; w++) {
            wf[2 * w]     = bf2f(aw[w] & 0xffff);
            wf[2 * w + 1] = bf2f(aw[w] >> 16);
        }
        int cc = cb8 * 8;
#pragma unroll
        for (int rr = 0; rr < 16; rr++) {
            const float* tr = &tpsS[rbase + rr][cc];
            float4 t0 = *(const float4*)tr;
            float4 t1 = *(const float4*)(tr + 4);
            acc[rr] += wf[0] * t0.x + wf[1] * t0.y + wf[2] * t0.z + wf[3] * t0.w
                     + wf[4] * t1.x + wf[5] * t1.y + wf[6] * t1.z + wf[7] * t1.w;
        }
    }
#pragma unroll
    for (int rr = 0; rr < 16; rr++) {
        int r = r0 + rbase + rr;
        int b2 = r / 192, p = r - b2 * 192;
        float res = x[((size_t)b2 * T0 + (T0 - PRED) + p) * CIN + o];
        out[(size_t)r * TGT + o] = res + acc[rr] + pbv * wsS[rbase + rr]
                                 + schv * btS[rbase + rr] + bchv;
    }
}

extern "C" void kernel_launch(void* const* d_in, const int* in_sizes, int n_in,
                              void* d_out, int out_size, void* d_ws, size_t ws_size,
                              hipStream_t stream) {
    const float* x    = (const float*)d_in[0];
    const float* dw_w = (const float*)d_in[1];
    const float* dw_b = (const float*)d_in[2];
    const float* pw_w = (const float*)d_in[3];
    const float* pw_b = (const float*)d_in[4];
    const float* wt0  = (const float*)d_in[5];
    const float* bt0  = (const float*)d_in[6];
    const float* wt1  = (const float*)d_in[7];
    const float* bt1  = (const float*)d_in[8];
    const float* wt2  = (const float*)d_in[9];
    const float* bt2  = (const float*)d_in[10];
    const float* w_ch = (const float*)d_in[11];
    const float* b_ch = (const float*)d_in[12];
    const float* slog = (const float*)d_in[13];
    float* out = (float*)d_out;
    float* ws  = (float*)d_ws;

    float* xct    = ws + XCT_OFF;
    float* s1b    = ws + S1_OFF;
    float* s2b    = ws + S2_OFF;
    float* parts  = ws + P0_OFF;
    float* parts2 = ws + PARTS2_OFF;
    int*   freqs  = (int*)(ws + META_OFF);
    float* wkb    = ws + META_OFF + 16;
    float* swb    = ws + META_OFF + 32;
    unsigned short* w2tb = (unsigned short*)(ws + W2T_OFF);
    float* pbs    = ws + PBS_OFF;
    float* wsumb  = ws + WSUM_OFF;
    unsigned short* wtb  = (unsigned short*)(ws + WTB_OFF);
    unsigned short* dwm0 = (unsigned short*)(ws + DWM0_OFF);
    unsigned short* dwm1 = (unsigned short*)(ws + DWM1_OFF);
    unsigned short* dwm2 = (unsigned short*)(ws + DWM2_OFF);
    unsigned short* tpb  = (unsigned short*)(ws + TP_OFF);

    front<<<dim3(32, 4, NB), dim3(32, 8, 1), 0, stream>>>(x, xct, s1b, s2b);
    fft_all<<<dim3(1024, 3), 256, 0, stream>>>(xct, s1b, s2b, parts);
    reduce_partA<<<dim3(9, 3, 16), 256, 0, stream>>>(parts, parts2);
    meta_topk<<<3, 256, 0, stream>>>(parts2, slog, freqs, wkb, swb);
    prep_all<<<209, 256, 0, stream>>>(w_ch, pw_w, pw_b, wt0, wt1, wt2,
                                      w2tb, pbs, wtb, wsumb);
    dwmix_all<<<dim3(32, NB, 3), 256, 0, stream>>>(xct, s1b, s2b, dw_w, dw_b,
                                                   freqs, wkb, dwm0, dwm1, dwm2);
    tp_gemm_all<<<dim3(3, 128, 3), 256, 0, stream>>>(wtb, dwm0, dwm1, dwm2, tpb);
    final_out<<<384, 256, 0, stream>>>(x, tpb, w2tb, pbs, wsumb,
                                       bt0, bt1, bt2, b_ch, swb, out);
}

// Round 8
// 197.202 us; speedup vs baseline: 1.3656x; 1.3606x over previous
//
#include <hip/hip_runtime.h>
#include <math.h>

#define NB   64
#define T0   1024
#define CIN  128
#define HID  256
#define TGT  128
#define PRED 192
#define NROWS (NB*CIN)
#define KTOT 1792   // 1024+512+256

typedef __attribute__((ext_vector_type(4))) float f32x4;
typedef __attribute__((ext_vector_type(8))) short s16x8;

// ---------------- workspace layout (float offsets) ----------------
static const size_t XCT_OFF    = 0;          // [64][128][1024] f32
static const size_t S1_OFF     = 8388608;    // [64][128][512]
static const size_t S2_OFF     = 12582912;   // [64][128][256]
static const size_t P0_OFF     = 14680064;   // fft partials [1024][520+264+136]
static const size_t PARTS2_OFF = 15622144;   // [3][16][520]
static const size_t META_OFF   = 15647104;   // freqs int[9]@0, wk f32[9]@16, sw f32[3]@32
static const size_t W2T_OFF    = 15647168;   // [128 o][128 c-swizzled] bf16
static const size_t PBS_OFF    = 15655360;   // Pb[128], S_ch[128]
static const size_t WSUM_OFF   = 15655616;   // [3][192] (sw-prescaled)
static const size_t TB32_OFF   = 15656192;   // u32 [3][1024] base pairs
static const size_t TB16_OFF   = 15659264;   // u16 [3][1024] base k2
static const size_t WTB_OFF    = 15660800;   // bf16 [192][1792] sw-prescaled
static const size_t DWM_OFF    = 15832832;   // bf16 [8192][1792]
static const size_t TP_OFF     = 23172864;   // bf16 [192][8192]
// end = 23959296 floats = 95.8 MB

__device__ inline unsigned short f2bf(float x) {
    union { float f; unsigned u; } v; v.f = x;
    unsigned r = (v.u + 0x7FFFu + ((v.u >> 16) & 1u)) >> 16;
    return (unsigned short)r;
}
__device__ inline float bf2f(unsigned short u) {
    union { unsigned u; float f; } v; v.u = ((unsigned)u) << 16;
    return v.f;
}

// ---------------- fused: transpose x[B,T,C]->xct[B,C,T] + pool1 + pool2 ----------------
__global__ __launch_bounds__(256) void front(const float* __restrict__ x,
        float* __restrict__ xct, float* __restrict__ s1, float* __restrict__ s2) {
    __shared__ float tile[32][33];
    int b = blockIdx.z;
    int t0 = blockIdx.x * 32, c0 = blockIdx.y * 32;
    int tx = threadIdx.x, ty = threadIdx.y;       // 32 x 8
#pragma unroll
    for (int i = 0; i < 4; i++) {
        int t = t0 + ty + i * 8, c = c0 + tx;
        tile[ty + i * 8][tx] = x[((size_t)b * T0 + t) * CIN + c];
    }
    __syncthreads();
#pragma unroll
    for (int i = 0; i < 4; i++) {
        int c = c0 + ty + i * 8, cc = ty + i * 8;
        xct[((size_t)b * CIN + c) * T0 + t0 + tx] = tile[tx][cc];
        if (tx < 16) {
            float v = 0.5f * (tile[2 * tx][cc] + tile[2 * tx + 1][cc]);
            s1[((size_t)b * CIN + c) * (T0 / 2) + t0 / 2 + tx] = v;
        }
        if (tx < 8) {
            float v = 0.25f * (tile[4 * tx][cc] + tile[4 * tx + 1][cc]
                             + tile[4 * tx + 2][cc] + tile[4 * tx + 3][cc]);
            s2[((size_t)b * CIN + c) * (T0 / 4) + t0 / 4 + tx] = v;
        }
    }
}

// ---------------- FFT body: 2 real rows per complex FFT, double-stage radix-2 ----------------
#define PHYS(i) ((i) + ((i) >> 5))
template<int LOGT>
__device__ __forceinline__ void fft_body(const float* __restrict__ xm,
        float* __restrict__ part, int pad,
        float* re, float* im, float* twc, float* tws, float* acc) {
    constexpr int T = 1 << LOGT;
    constexpr int F = T / 2;
    int tid = threadIdx.x;
    for (int j = tid; j < F; j += 256) {
        float s, c;
        sincosf(-6.283185307179586f * (float)j / (float)T, &s, &c);
        twc[PHYS(j)] = c; tws[PHYS(j)] = s;
    }
    for (int i = tid; i <= F; i += 256) acc[i] = 0.f;
    __syncthreads();

    int rowbase = blockIdx.x * 8;
    for (int pr = 0; pr < 4; pr++) {
        const float* row0 = xm + (size_t)(rowbase + 2 * pr) * T;
        const float* row1 = row0 + T;
        for (int j = tid; j < T; j += 256) {
            int rv = (int)(__brev((unsigned)j) >> (32 - LOGT));
            re[PHYS(rv)] = row0[j];
            im[PHYS(rv)] = row1[j];
        }
        __syncthreads();
        for (int s = 1; s + 1 <= LOGT; s += 2) {
            int mh = 1 << (s - 1);
            if (tid < T / 4) {
                int k  = tid & (mh - 1);
                int gq = tid >> (s - 1);
                int i0 = (gq << (s + 1)) + k;
                int iA = PHYS(i0), iB = PHYS(i0 + mh);
                int iC = PHYS(i0 + 2 * mh), iD = PHYS(i0 + 3 * mh);
                int t1 = PHYS(k << (LOGT - s));
                int t2 = PHYS(k << (LOGT - s - 1));
                int t3 = PHYS((k + mh) << (LOGT - s - 1));
                float w1r = twc[t1], w1i = tws[t1];
                float w2r = twc[t2], w2i = tws[t2];
                float w3r = twc[t3], w3i = tws[t3];
                float ar = re[iA], ai = im[iA];
                float br = re[iB], bi = im[iB];
                float cr = re[iC], ci = im[iC];
                float dr = re[iD], di = im[iD];
                float tbr = w1r * br - w1i * bi, tbi = w1r * bi + w1i * br;
                float tdr = w1r * dr - w1i * di, tdi = w1r * di + w1i * dr;
                float v0r = ar + tbr, v0i = ai + tbi;
                float v1r = ar - tbr, v1i = ai - tbi;
                float v2r = cr + tdr, v2i = ci + tdi;
                float v3r = cr - tdr, v3i = ci - tdi;
                float t2r = w2r * v2r - w2i * v2i, t2i = w2r * v2i + w2i * v2r;
                float t3r = w3r * v3r - w3i * v3i, t3i = w3r * v3i + w3i * v3r;
                re[iA] = v0r + t2r; im[iA] = v0i + t2i;
                re[iC] = v0r - t2r; im[iC] = v0i - t2i;
                re[iB] = v1r + t3r; im[iB] = v1i + t3i;
                re[iD] = v1r - t3r; im[iD] = v1i - t3i;
            }
            __syncthreads();
        }
        if (LOGT & 1) {
            constexpr int s = LOGT;
            int mh = 1 << (s - 1);
            if (tid < T / 2) {
                int k  = tid & (mh - 1);
                int i1 = PHYS(tid);
                int i2 = PHYS(tid + mh);
                int tw = PHYS(k);
                float wr = twc[tw], wi = tws[tw];
                float xr = re[i2], xi = im[i2];
                float tr = wr * xr - wi * xi;
                float ti = wr * xi + wi * xr;
                float ur = re[i1], ui = im[i1];
                re[i1] = ur + tr; im[i1] = ui + ti;
                re[i2] = ur - tr; im[i2] = ui - ti;
            }
            __syncthreads();
        }
        for (int f = tid; f <= F; f += 256) {
            if (f >= 1) {
                int mf = T - f;
                float rf = re[PHYS(f)], imf = im[PHYS(f)];
                float rm = re[PHYS(mf)], imm = im[PHYS(mf)];
                float m0 = sqrtf((rf + rm) * (rf + rm) + (imf - imm) * (imf - imm));
                float m1 = sqrtf((imf + imm) * (imf + imm) + (rf - rm) * (rf - rm));
                acc[f] += 0.5f * (m0 + m1);
            }
        }
        __syncthreads();
    }
    for (int f = tid; f <= F; f += 256)
        part[(size_t)blockIdx.x * pad + f] = acc[f];
}

__global__ __launch_bounds__(256) void fft_all(const float* __restrict__ xct,
        const float* __restrict__ s1, const float* __restrict__ s2,
        float* __restrict__ parts) {
    __shared__ float re[1056], im[1056], twc[528], tws[528], acc[513];
    int sc = blockIdx.y;
    if (sc == 0)
        fft_body<10>(xct, parts, 520, re, im, twc, tws, acc);
    else if (sc == 1)
        fft_body<9>(s1, parts + (size_t)1024 * 520, 264, re, im, twc, tws, acc);
    else
        fft_body<8>(s2, parts + (size_t)1024 * 520 + (size_t)1024 * 264, 136,
                    re, im, twc, tws, acc);
}

// ---------------- stage A: sum 64 rows per block -> parts2[s][16][520] ----------------
__global__ __launch_bounds__(256) void reduce_partA(const float* __restrict__ parts,
                                                    float* __restrict__ parts2) {
    const int PADs[3] = {520, 264, 136};
    const int Fs[3]   = {513, 257, 129};
    const size_t POFF[3] = {0, (size_t)1024 * 520, (size_t)1024 * 520 + (size_t)1024 * 264};
    int s  = blockIdx.y;
    int rs = blockIdx.z;
    int fl = threadIdx.x & 63;
    int rg = threadIdx.x >> 6;
    int f  = blockIdx.x * 64 + fl;
    bool valid = f < Fs[s];
    const float* base = parts + POFF[s];
    int pad = PADs[s];
    float sum = 0.f;
    if (valid) {
        int r0 = rs * 64 + rg * 16;
#pragma unroll
        for (int i = 0; i < 16; i++) sum += base[(size_t)(r0 + i) * pad + f];
    }
    __shared__ float red[256];
    red[threadIdx.x] = sum;
    __syncthreads();
    if (rg == 0 && valid) {
        float tot = red[fl] + red[fl + 64] + red[fl + 128] + red[fl + 192];
        parts2[(size_t)(s * 16 + rs) * 520 + f] = tot;
    }
}

__device__ inline float sum16(const float* __restrict__ p2, int m, int f) {
    const float* b = p2 + (size_t)m * 16 * 520 + f;
    float s = 0.f;
#pragma unroll
    for (int r = 0; r < 16; r++) s += b[r * 520];
    return s;
}

// ---------------- top-3 + geometry base-tables ----------------
__device__ inline void ins3(float v, int i, float& b0, int& c0,
                            float& b1, int& c1, float& b2, int& c2) {
    bool g0 = (v > b0) || (v == b0 && i < c0);
    bool g1 = (v > b1) || (v == b1 && i < c1);
    bool g2 = (v > b2) || (v == b2 && i < c2);
    if (g0)      { b2 = b1; c2 = c1; b1 = b0; c1 = c0; b0 = v; c0 = i; }
    else if (g1) { b2 = b1; c2 = c1; b1 = v; c1 = i; }
    else if (g2) { b2 = v; c2 = i; }
}

__global__ __launch_bounds__(256) void meta_topk(const float* __restrict__ parts2,
                          const float* __restrict__ slog,
                          int* __restrict__ freqs, float* __restrict__ wk,
                          float* __restrict__ sw,
                          unsigned* __restrict__ tb32g, unsigned short* __restrict__ tb16g) {
    __shared__ float sv[12];
    __shared__ int   si[12];
    __shared__ int   sfr[3];
    const int Fs[3] = {513, 257, 129};
    const int Ts[3] = {1024, 512, 256};
    int m = blockIdx.x;
    int tid = threadIdx.x, lane = tid & 63, wv = tid >> 6;
    int F = Fs[m];
    float b0 = -1e30f, b1 = -1e30f, b2 = -1e30f;
    int   c0 = 0x7fffffff, c1 = 0x7fffffff, c2 = 0x7fffffff;
    for (int i = tid; i < F; i += 256) {
        float v = (i == 0) ? 0.f : sum16(parts2, m, i) * (1.f / 8192.f);
        ins3(v, i, b0, c0, b1, c1, b2, c2);
    }
#pragma unroll
    for (int d = 1; d < 64; d <<= 1) {
        float o0 = __shfl_xor(b0, d), o1 = __shfl_xor(b1, d), o2 = __shfl_xor(b2, d);
        int   i0 = __shfl_xor(c0, d), i1 = __shfl_xor(c1, d), i2 = __shfl_xor(c2, d);
        ins3(o0, i0, b0, c0, b1, c1, b2, c2);
        ins3(o1, i1, b0, c0, b1, c1, b2, c2);
        ins3(o2, i2, b0, c0, b1, c1, b2, c2);
    }
    if (lane == 0) {
        sv[wv * 3 + 0] = b0; si[wv * 3 + 0] = c0;
        sv[wv * 3 + 1] = b1; si[wv * 3 + 1] = c1;
        sv[wv * 3 + 2] = b2; si[wv * 3 + 2] = c2;
    }
    __syncthreads();
    if (tid == 0) {
        float d0 = sv[0], d1 = sv[1], d2 = sv[2];
        int   e0 = si[0], e1 = si[1], e2 = si[2];
        for (int q = 3; q < 12; q++) ins3(sv[q], si[q], d0, e0, d1, e1, d2, e2);
        int fr[3] = {max(1, e0), max(1, e1), max(1, e2)};
        float av[3];
#pragma unroll
        for (int i = 0; i < 3; i++) av[i] = sum16(parts2, m, fr[i]) * (1.f / 8192.f);
        float mx = fmaxf(av[0], fmaxf(av[1], av[2]));
        float x0 = expf(av[0] - mx), x1 = expf(av[1] - mx), x2 = expf(av[2] - mx);
        float inv = 1.f / (x0 + x1 + x2);
        freqs[m * 3 + 0] = fr[0]; freqs[m * 3 + 1] = fr[1]; freqs[m * 3 + 2] = fr[2];
        wk[m * 3 + 0] = x0 * inv; wk[m * 3 + 1] = x1 * inv; wk[m * 3 + 2] = x2 * inv;
        sfr[0] = fr[0]; sfr[1] = fr[1]; sfr[2] = fr[2];
        if (m == 0) {
            float s0 = slog[0], s1 = slog[1], s2 = slog[2];
            float mx2 = fmaxf(s0, fmaxf(s1, s2));
            float e0b = expf(s0 - mx2), e1b = expf(s1 - mx2), e2b = expf(s2 - mx2);
            float inv2 = 3.f / (e0b + e1b + e2b);
            sw[0] = e0b * inv2; sw[1] = e1b * inv2; sw[2] = e2b * inv2;
        }
    }
    __syncthreads();
    // geometry: absolute xpad base per (k,l); halo layout (rows+2)x(p+2)
    int Tm = Ts[m];
    int p0 = Tm / sfr[0], p1 = Tm / sfr[1], p2v = Tm / sfr[2];
    int r0n = (Tm + p0 - 1) / p0, r1n = (Tm + p1 - 1) / p1;
    int off0 = 0;
    int off1 = (r0n + 2) * (p0 + 2);
    int off2 = off1 + (r1n + 2) * (p1 + 2);
    for (int l = tid; l < Tm; l += 256) {
        int ra = l / p0, ca = l - ra * p0;
        int rb = l / p1, cb = l - rb * p1;
        int rc = l / p2v, cc = l - rc * p2v;
        unsigned ba = off0 + (ra + 1) * (p0 + 2) + ca + 1;
        unsigned bb = off1 + (rb + 1) * (p1 + 2) + cb + 1;
        unsigned bc = off2 + (rc + 1) * (p2v + 2) + cc + 1;
        tb32g[m * 1024 + l] = ba | (bb << 16);
        tb16g[m * 1024 + l] = (unsigned short)bc;
    }
}

// ---------------- prep: W2 fold + biases + sw-prescaled w_t->bf16 + row sums ----------------
__global__ __launch_bounds__(256) void prep_all(const float* __restrict__ w_ch,
        const float* __restrict__ pw_w, const float* __restrict__ pw_b,
        const float* __restrict__ wt0, const float* __restrict__ wt1,
        const float* __restrict__ wt2, const float* __restrict__ swb,
        unsigned short* __restrict__ w2ot, float* __restrict__ pbs,
        unsigned short* __restrict__ wtb, float* __restrict__ wsum) {
    int tid = threadIdx.x;
    int bx = blockIdx.x;
    if (bx < 64) {
        int idx = bx * 256 + tid;
        int c = idx >> 7, o = idx & 127;
        float acc = 0.f;
        for (int h = 0; h < HID; h++) acc += w_ch[o * HID + h] * pw_w[h * CIN + c];
        w2ot[o * 128 + (c ^ ((o & 7) << 3))] = f2bf(acc);
        return;
    }
    if (bx == 64) {
        if (tid < 128) {
            float pb = 0.f, s = 0.f;
            for (int h = 0; h < HID; h++) {
                float w = w_ch[tid * HID + h];
                pb += w * pw_b[h]; s += w;
            }
            pbs[tid] = pb; pbs[128 + tid] = s;
        }
        return;
    }
    int wid = (bx - 65) * 4 + (tid >> 6);
    int lane = tid & 63;
    const float* src; int T, p, m; int moff;
    if (wid < 192)      { m = 0; p = wid;       src = wt0; T = 1024; moff = 0; }
    else if (wid < 384) { m = 1; p = wid - 192; src = wt1; T = 512;  moff = 1024; }
    else                { m = 2; p = wid - 384; src = wt2; T = 256;  moff = 1536; }
    float swm = swb[m];
    const float* row = src + (size_t)p * T;
    unsigned short* dst = wtb + (size_t)p * KTOT + moff;
    float s = 0.f;
    for (int j = lane; j < T; j += 64) {
        float v = row[j] * swm; s += v; dst[j] = f2bf(v);
    }
#pragma unroll
    for (int d = 1; d < 64; d <<= 1) s += __shfl_xor(s, d);
    if (lane == 0) wsum[m * 192 + p] = s;
}

// ---------------- depthwise mix: haloed folded grids in LDS, no masks ----------------
template<int T>
__device__ __forceinline__ void dwmix_body(const float* __restrict__ xm,
        const float* __restrict__ dw_w, const float* __restrict__ dw_b,
        const int* __restrict__ freqs, const float* __restrict__ wkbuf,
        const unsigned* __restrict__ tb32g, const unsigned short* __restrict__ tb16g,
        int m, int moff, unsigned short* __restrict__ dwm, float* xs) {
    int tid = threadIdx.x;
    int c = blockIdx.x, b = blockIdx.y;
    int pp[3]; float wkv[3]; int tot;
    {
        int off = 0;
#pragma unroll
        for (int k = 0; k < 3; k++) {
            int f = freqs[m * 3 + k];
            int p = T / f;
            pp[k] = p + 2;
            int rows = (T + p - 1) / p;
            off += (rows + 2) * (p + 2);
            wkv[k] = wkbuf[m * 3 + k];
        }
        tot = off;
    }
    for (int i = tid; i < tot; i += 256) xs[i] = 0.f;
    __syncthreads();
    const float* src = xm + ((size_t)b * CIN + c) * T;
    const unsigned* t32 = tb32g + m * 1024;
    const unsigned short* t16 = tb16g + m * 1024;
#pragma unroll
    for (int i = 0; i < T / 256; i++) {
        int l = i * 256 + tid;
        float xv = src[l];
        unsigned w32 = t32[l];
        int b0 = w32 & 0xffff, b1 = w32 >> 16, b2 = t16[l];
        xs[b0] = xv; xs[b1] = xv; xs[b2] = xv;
    }
    __syncthreads();

    float wk9[27];
#pragma unroll
    for (int k = 0; k < 3; k++)
#pragma unroll
        for (int q = 0; q < 9; q++) wk9[k * 9 + q] = wkv[k] * dw_w[c * 9 + q];
    float bias = dw_b[c];
    unsigned short* outp = dwm + (size_t)(b * CIN + c) * KTOT + moff;
    int P0 = pp[0], P1 = pp[1], P2 = pp[2];

#pragma unroll
    for (int i = 0; i < T / 256; i++) {
        int l = i * 256 + tid;
        unsigned w32 = t32[l];
        int b2v = t16[l];
        int b0 = w32 & 0xffff, b1 = w32 >> 16;
        float s = bias;
        {
            const float* q = xs + b0;
            s += wk9[0] * q[-P0 - 1] + wk9[1] * q[-P0] + wk9[2] * q[-P0 + 1]
               + wk9[3] * q[-1]      + wk9[4] * q[0]   + wk9[5] * q[1]
               + wk9[6] * q[P0 - 1]  + wk9[7] * q[P0]  + wk9[8] * q[P0 + 1];
        }
        {
            const float* q = xs + b1;
            s += wk9[9]  * q[-P1 - 1] + wk9[10] * q[-P1] + wk9[11] * q[-P1 + 1]
               + wk9[12] * q[-1]      + wk9[13] * q[0]   + wk9[14] * q[1]
               + wk9[15] * q[P1 - 1]  + wk9[16] * q[P1]  + wk9[17] * q[P1 + 1];
        }
        {
            const float* q = xs + b2v;
            s += wk9[18] * q[-P2 - 1] + wk9[19] * q[-P2] + wk9[20] * q[-P2 + 1]
               + wk9[21] * q[-1]      + wk9[22] * q[0]   + wk9[23] * q[1]
               + wk9[24] * q[P2 - 1]  + wk9[25] * q[P2]  + wk9[26] * q[P2 + 1];
        }
        outp[l] = f2bf(s);
    }
}

__global__ __launch_bounds__(256) void dwmix_all(const float* __restrict__ xct,
        const float* __restrict__ s1, const float* __restrict__ s2,
        const float* __restrict__ dw_w, const float* __restrict__ dw_b,
        const int* __restrict__ freqs, const float* __restrict__ wkbuf,
        const unsigned* __restrict__ tb32g, const unsigned short* __restrict__ tb16g,
        unsigned short* __restrict__ dwm) {
    __shared__ float xs[7296];   // worst-case sum of 3 haloed grids (f={1,2,3} @ T=1024)
    int sc = blockIdx.z;
    if (sc == 0)
        dwmix_body<1024>(xct, dw_w, dw_b, freqs, wkbuf, tb32g, tb16g, 0, 0, dwm, xs);
    else if (sc == 1)
        dwmix_body<512>(s1, dw_w, dw_b, freqs, wkbuf, tb32g, tb16g, 1, 1024, dwm, xs);
    else
        dwmix_body<256>(s2, dw_w, dw_b, freqs, wkbuf, tb32g, tb16g, 2, 1536, dwm, xs);
}

// ---------------- tp GEMM: C[192][8192] = wtb[192][1792] * dwm[8192][1792]^T ----------------
__global__ __launch_bounds__(256) void tp_gemm(const unsigned short* __restrict__ A,
        const unsigned short* __restrict__ B, unsigned short* __restrict__ C) {
    __shared__ __align__(16) unsigned short As[64 * 72];
    __shared__ __align__(16) unsigned short Bs[64 * 72];
    int tid = threadIdx.x;
    int lane = tid & 63, wave = tid >> 6;
    int wm = (wave >> 1) * 32, wn = (wave & 1) * 32;
    int p0 = blockIdx.x * 64, n0 = blockIdx.y * 64;
    f32x4 acc[2][2];
#pragma unroll
    for (int i = 0; i < 2; i++)
#pragma unroll
        for (int j = 0; j < 2; j++) acc[i][j] = (f32x4){0.f, 0.f, 0.f, 0.f};

    int r = tid >> 2, seg = tid & 3;
    const unsigned short* ga = A + (size_t)(p0 + r) * KTOT + seg * 16;
    const unsigned short* gb = B + (size_t)(n0 + r) * KTOT + seg * 16;
    unsigned short* la = &As[r * 72 + seg * 16];
    unsigned short* lb = &Bs[r * 72 + seg * 16];
    int fr = lane & 15, fk = (lane >> 4) * 8;

    for (int k0 = 0; k0 < KTOT; k0 += 64) {
        __syncthreads();
        *(uint4*)la       = *(const uint4*)ga;
        *(uint4*)(la + 8) = *(const uint4*)(ga + 8);
        *(uint4*)lb       = *(const uint4*)gb;
        *(uint4*)(lb + 8) = *(const uint4*)(gb + 8);
        ga += 64; gb += 64;
        __syncthreads();
#pragma unroll
        for (int ks = 0; ks < 2; ks++) {
            int ko = ks * 32 + fk;
            s16x8 a0 = *(const s16x8*)&As[(wm + fr) * 72 + ko];
            s16x8 a1 = *(const s16x8*)&As[(wm + 16 + fr) * 72 + ko];
            s16x8 b0 = *(const s16x8*)&Bs[(wn + fr) * 72 + ko];
            s16x8 b1 = *(const s16x8*)&Bs[(wn + 16 + fr) * 72 + ko];
            acc[0][0] = __builtin_amdgcn_mfma_f32_16x16x32_bf16(a0, b0, acc[0][0], 0, 0, 0);
            acc[0][1] = __builtin_amdgcn_mfma_f32_16x16x32_bf16(a0, b1, acc[0][1], 0, 0, 0);
            acc[1][0] = __builtin_amdgcn_mfma_f32_16x16x32_bf16(a1, b0, acc[1][0], 0, 0, 0);
            acc[1][1] = __builtin_amdgcn_mfma_f32_16x16x32_bf16(a1, b1, acc[1][1], 0, 0, 0);
        }
    }
    int crow = (lane >> 4) * 4, ccol = lane & 15;
#pragma unroll
    for (int i = 0; i < 2; i++)
#pragma unroll
        for (int j = 0; j < 2; j++) {
            int col = n0 + wn + j * 16 + ccol;
#pragma unroll
            for (int reg = 0; reg < 4; reg++) {
                int row = p0 + wm + i * 16 + crow + reg;
                C[(size_t)row * 8192 + col] = f2bf(acc[i][j][reg]);
            }
        }
}

// ---------------- final: out = residual + W2@tps + biases ----------------
__global__ __launch_bounds__(256) void final_out(const float* __restrict__ x,
        const unsigned short* __restrict__ tp, const unsigned short* __restrict__ w2ot,
        const float* __restrict__ pbs, const float* __restrict__ wsum,
        const float* __restrict__ bt0, const float* __restrict__ bt1,
        const float* __restrict__ bt2, const float* __restrict__ b_ch,
        const float* __restrict__ swb, float* __restrict__ out) {
    __shared__ unsigned short w2s[128 * 128];
    __shared__ float tpsS[32][128];
    __shared__ float wsS[32], btS[32];
    int tid = threadIdx.x;
    int r0 = blockIdx.x * 32;
    float sw0 = swb[0], sw1 = swb[1], sw2 = swb[2];

#pragma unroll
    for (int i = 0; i < 8; i++)
        ((uint4*)w2s)[i * 256 + tid] = ((const uint4*)w2ot)[i * 256 + tid];
#pragma unroll
    for (int it = 0; it < 2; it++) {
        int idx = tid + it * 256;
        int rr = idx >> 4, u = idx & 15;
        int r = r0 + rr;
        int b2 = r / 192, p2 = r - b2 * 192;
        size_t base = (size_t)p2 * 8192 + (size_t)b2 * 128 + u * 8;
        uint4 q0 = *(const uint4*)&tp[base];
        const unsigned* a0 = (const unsigned*)&q0;
        float o8[8];
#pragma unroll
        for (int w = 0; w < 4; w++) {
            o8[2 * w]     = bf2f(a0[w] & 0xffff);
            o8[2 * w + 1] = bf2f(a0[w] >> 16);
        }
        *(float4*)&tpsS[rr][u * 8]     = *(float4*)&o8[0];
        *(float4*)&tpsS[rr][u * 8 + 4] = *(float4*)&o8[4];
    }
    if (tid < 32) {
        int r = r0 + tid;
        int b2 = r / 192, p = r - b2 * 192;
        wsS[tid] = wsum[p] + wsum[192 + p] + wsum[384 + p];   // already sw-scaled
        btS[tid] = sw0 * bt0[p] + sw1 * bt1[p] + sw2 * bt2[p];
    }
    __syncthreads();

    int o = tid & 127, half = tid >> 7;
    int rbase = half * 16;
    float pbv  = pbs[o];
    float schv = pbs[128 + o];
    float bchv = (sw0 + sw1 + sw2) * b_ch[o];
    float acc[16];
#pragma unroll
    for (int rr = 0; rr < 16; rr++) acc[rr] = 0.f;

#pragma unroll 2
    for (int cb8 = 0; cb8 < 16; cb8++) {
        uint4 wv = *(const uint4*)&w2s[o * 128 + ((cb8 ^ (o & 7)) << 3)];
        const unsigned* aw = (const unsigned*)&wv;
        float wf[8];
#pragma unroll
        for (int w = 0; w < 4; w++) {
            wf[2 * w]     = bf2f(aw[w] & 0xffff);
            wf[2 * w + 1] = bf2f(aw[w] >> 16);
        }
        int cc = cb8 * 8;
#pragma unroll
        for (int rr = 0; rr < 16; rr++) {
            const float* tr = &tpsS[rbase + rr][cc];
            float4 t0 = *(const float4*)tr;
            float4 t1 = *(const float4*)(tr + 4);
            acc[rr] += wf[0] * t0.x + wf[1] * t0.y + wf[2] * t0.z + wf[3] * t0.w
                     + wf[4] * t1.x + wf[5] * t1.y + wf[6] * t1.z + wf[7] * t1.w;
        }
    }
#pragma unroll
    for (int rr = 0; rr < 16; rr++) {
        int r = r0 + rbase + rr;
        int b2 = r / 192, p = r - b2 * 192;
        float res = x[((size_t)b2 * T0 + (T0 - PRED) + p) * CIN + o];
        out[(size_t)r * TGT + o] = res + acc[rr] + pbv * wsS[rbase + rr]
                                 + schv * btS[rbase + rr] + bchv;
    }
}

extern "C" void kernel_launch(void* const* d_in, const int* in_sizes, int n_in,
                              void* d_out, int out_size, void* d_ws, size_t ws_size,
                              hipStream_t stream) {
    const float* x    = (const float*)d_in[0];
    const float* dw_w = (const float*)d_in[1];
    const float* dw_b = (const float*)d_in[2];
    const float* pw_w = (const float*)d_in[3];
    const float* pw_b = (const float*)d_in[4];
    const float* wt0  = (const float*)d_in[5];
    const float* bt0  = (const float*)d_in[6];
    const float* wt1  = (const float*)d_in[7];
    const float* bt1  = (const float*)d_in[8];
    const float* wt2  = (const float*)d_in[9];
    const float* bt2  = (const float*)d_in[10];
    const float* w_ch = (const float*)d_in[11];
    const float* b_ch = (const float*)d_in[12];
    const float* slog = (const float*)d_in[13];
    float* out = (float*)d_out;
    float* ws  = (float*)d_ws;

    float* xct    = ws + XCT_OFF;
    float* s1b    = ws + S1_OFF;
    float* s2b    = ws + S2_OFF;
    float* parts  = ws + P0_OFF;
    float* parts2 = ws + PARTS2_OFF;
    int*   freqs  = (int*)(ws + META_OFF);
    float* wkb    = ws + META_OFF + 16;
    float* swb    = ws + META_OFF + 32;
    unsigned short* w2tb = (unsigned short*)(ws + W2T_OFF);
    float* pbs    = ws + PBS_OFF;
    float* wsumb  = ws + WSUM_OFF;
    unsigned*       tb32g = (unsigned*)(ws + TB32_OFF);
    unsigned short* tb16g = (unsigned short*)(ws + TB16_OFF);
    unsigned short* wtb  = (unsigned short*)(ws + WTB_OFF);
    unsigned short* dwm  = (unsigned short*)(ws + DWM_OFF);
    unsigned short* tpb  = (unsigned short*)(ws + TP_OFF);

    front<<<dim3(32, 4, NB), dim3(32, 8, 1), 0, stream>>>(x, xct, s1b, s2b);
    fft_all<<<dim3(1024, 3), 256, 0, stream>>>(xct, s1b, s2b, parts);
    reduce_partA<<<dim3(9, 3, 16), 256, 0, stream>>>(parts, parts2);
    meta_topk<<<3, 256, 0, stream>>>(parts2, slog, freqs, wkb, swb, tb32g, tb16g);
    prep_all<<<209, 256, 0, stream>>>(w_ch, pw_w, pw_b, wt0, wt1, wt2, swb,
                                      w2tb, pbs, wtb, wsumb);
    dwmix_all<<<dim3(CIN, NB, 3), 256, 0, stream>>>(xct, s1b, s2b, dw_w, dw_b,
                                                    freqs, wkb, tb32g, tb16g, dwm);
    tp_gemm<<<dim3(3, 128), 256, 0, stream>>>(wtb, dwm, tpb);
    final_out<<<384, 256, 0, stream>>>(x, tpb, w2tb, pbs, wsumb,
                                       bt0, bt1, bt2, b_ch, swb, out);
}